// Round 5
// baseline (641.932 us; speedup 1.0000x reference)
//
#include <hip/hip_runtime.h>
#include <hip/hip_bf16.h>
#include <math.h>

#define T_TOK 8192
#define HDIM  1024
#define IDIM  4096
#define SDIM  128
#define TOPK  16

typedef __bf16 bf16x8 __attribute__((ext_vector_type(8)));
typedef float  f32x4  __attribute__((ext_vector_type(4)));

__device__ __forceinline__ unsigned short f2bf(float f) {
    union { float f; unsigned u; } a; a.f = f;
    unsigned r = a.u + 0x7fffu + ((a.u >> 16) & 1u);
    return (unsigned short)(r >> 16);
}
__device__ __forceinline__ float bf2f(unsigned short b) {
    union { unsigned u; float f; } a; a.u = ((unsigned)b) << 16;
    return a.f;
}

__device__ __forceinline__ void gld_lds16(const void* g, void* l) {
    __builtin_amdgcn_global_load_lds(
        (__attribute__((address_space(1))) void*)g,
        (__attribute__((address_space(3))) void*)l,
        16, 0, 0);
}

// ---------------- merged fp32 -> bf16 convert over 8 segments ----------------
struct CvtSegs {
    const float4* src[8];
    ushort4*      dst[8];
    int           end[8];   // prefix-sum of float4 counts
};

__global__ __launch_bounds__(256)
void cvt_all_kernel(CvtSegs segs) {
    int i = blockIdx.x * 256 + threadIdx.x;
    if (i >= segs.end[7]) return;
    int s = 0;
    #pragma unroll
    for (int k = 0; k < 7; ++k) s += (i >= segs.end[k]) ? 1 : 0;
    int base = (s == 0) ? 0 : segs.end[s - 1];
    int j = i - base;
    float4 v = segs.src[s][j];
    ushort4 o;
    o.x = f2bf(v.x); o.y = f2bf(v.y); o.z = f2bf(v.z); o.w = f2bf(v.w);
    segs.dst[s][j] = o;
}

// ---------------- generic C = A * B^T (bf16 in, fp32 out), 128x128 tile ----------------
// (kept only for the small router GEMM)
template<int ADD>
__global__ __launch_bounds__(256)
void gemm_bt(const unsigned short* __restrict__ A, const unsigned short* __restrict__ B,
             float* __restrict__ C, int M, int N, int K) {
    __shared__ unsigned short As[4096];  // [kc=4][m=128][8] bf16
    __shared__ unsigned short Bs[4096];  // [kc=4][n=128][8]
    const int tid  = threadIdx.x;
    const int lane = tid & 63;
    const int wave = tid >> 6;
    const int tm = blockIdx.x * 128;
    const int tn = blockIdx.y * 128;
    const int wm = (wave & 1) * 64;
    const int wn = (wave >> 1) * 64;
    const int quad = lane >> 4;
    const int tr   = lane & 15;

    f32x4 acc[4][4] = {};
    bf16x8 af[4], bfr[4];

    const int ua0 = tid,        am0 = ua0 & 127, ak0 = ua0 >> 7;
    const int ua1 = tid + 256,  am1 = ua1 & 127, ak1 = ua1 >> 7;

    auto issue = [&](int kt) {
        gld_lds16(A + (size_t)(tm + am0) * K + kt + ak0 * 8, &As[ua0 * 8]);
        gld_lds16(A + (size_t)(tm + am1) * K + kt + ak1 * 8, &As[ua1 * 8]);
        gld_lds16(B + (size_t)(tn + am0) * K + kt + ak0 * 8, &Bs[ua0 * 8]);
        gld_lds16(B + (size_t)(tn + am1) * K + kt + ak1 * 8, &Bs[ua1 * 8]);
    };
    auto rdfrags = [&]() {
        #pragma unroll
        for (int mi = 0; mi < 4; ++mi)
            af[mi] = *(const bf16x8*)&As[(quad * 128 + wm + mi * 16 + tr) * 8];
        #pragma unroll
        for (int ni = 0; ni < 4; ++ni)
            bfr[ni] = *(const bf16x8*)&Bs[(quad * 128 + wn + ni * 16 + tr) * 8];
    };
    auto mfmas = [&]() {
        #pragma unroll
        for (int mi = 0; mi < 4; ++mi)
            #pragma unroll
            for (int ni = 0; ni < 4; ++ni)
                acc[mi][ni] = __builtin_amdgcn_mfma_f32_16x16x32_bf16(af[mi], bfr[ni], acc[mi][ni], 0, 0, 0);
    };

    issue(0);
    asm volatile("s_waitcnt vmcnt(0)" ::: "memory");
    __syncthreads();
    rdfrags();
    for (int kt = 32; kt < K; kt += 32) {
        __syncthreads();
        issue(kt);
        mfmas();
        asm volatile("s_waitcnt vmcnt(0)" ::: "memory");
        __syncthreads();
        rdfrags();
    }
    mfmas();

    #pragma unroll
    for (int mi = 0; mi < 4; ++mi) {
        #pragma unroll
        for (int ni = 0; ni < 4; ++ni) {
            int col = tn + wn + ni * 16 + tr;
            #pragma unroll
            for (int r = 0; r < 4; ++r) {
                int row = tm + wm + mi * 16 + quad * 4 + r;
                size_t o = (size_t)row * N + col;
                float v = acc[mi][ni][r];
                if (ADD) v += C[o];
                C[o] = v;
            }
        }
    }
}

// common swizzle pieces for the ring kernels:
//   slotoff(row,cq) = (row>>1)*128 + ((((row&1)<<2)|cq) ^ ((row>>1)&7))*16
#define BARX() asm volatile("s_barrier" ::: "memory")
#define VMW(n) asm volatile("s_waitcnt vmcnt(" #n ")" ::: "memory")

// ---------------- fused GEMM1, 256x256 tile, BK=32 ring-4, 1 barrier/tile ----------------
// h = silu(x @ Wg^T) * (x @ Wu^T), bf16 out. Virtual interleaved Wcat as before.
// Ring: 4 slots per operand. Tile t stages slots for tile t+3; VMW(8)+BARX once per tile
// (after MFMAs) retires tile t+1's DMA and publishes it. Single barrier per tile: each
// wave's ds_reads of slot r complete before its own MFMAs (lgkmcnt), hence before the
// barrier, hence before any wave's next-tile overwrite issue. Waves stagger within the
// tile -> LDS drain overlaps MFMA across waves.
// XCD map: each XCD owns 4 gm (2MB A, L2-resident) x all 32 gn (B streams).
#define RD_A(r, MB) { const char* _p = lds + ((r) << 14); \
    af[0] = *(const bf16x8*)(_p + aoff[(MB)+0]); \
    af[1] = *(const bf16x8*)(_p + aoff[(MB)+1]); \
    af[2] = *(const bf16x8*)(_p + aoff[(MB)+2]); \
    af[3] = *(const bf16x8*)(_p + aoff[(MB)+3]); }

#define RD_B(r) { const char* _p = lds + 65536 + ((r) << 14); \
    bfv[0] = *(const bf16x8*)(_p + boff[0]); \
    bfv[1] = *(const bf16x8*)(_p + boff[1]); \
    bfv[2] = *(const bf16x8*)(_p + boff[2]); \
    bfv[3] = *(const bf16x8*)(_p + boff[3]); }

#define MMA16(ACC) { __builtin_amdgcn_s_setprio(1); \
    _Pragma("unroll") \
    for (int _i = 0; _i < 4; ++_i) \
        _Pragma("unroll") \
        for (int _n = 0; _n < 4; ++_n) \
            ACC[_i][_n] = __builtin_amdgcn_mfma_f32_16x16x32_bf16(af[_i], bfv[_n], ACC[_i][_n], 0, 0, 0); \
    __builtin_amdgcn_s_setprio(0); }

__global__ __launch_bounds__(512, 2)
void gemm1_8ph(const unsigned short* __restrict__ Xb, const unsigned short* __restrict__ Wg,
               const unsigned short* __restrict__ Wu, unsigned short* __restrict__ Hb) {
    __shared__ __align__(16) char lds[131072];
    const int tid  = threadIdx.x;
    const int lane = tid & 63;
    const int wid  = tid >> 6;
    const int quad = lane >> 4;
    const int tr   = lane & 15;
    const int wm   = (wid >> 2) << 7;   // 0 / 128
    const int wn   = (wid & 3) << 6;    // 0 / 64 / 128 / 192

    // XCD map: xcd = bid&7 owns gm in {xcd*4 .. xcd*4+3} (A 2MB, L2-resident), gn sweeps 0..31.
    const int bid = blockIdx.x;
    const int u   = bid >> 3;
    const int gm  = (((bid & 7) << 2) | (u & 3)) << 8;
    const int gn  = (u >> 2) << 8;

    // staging thread map (inverse of the LDS swizzle, so gld_lds dest stays linear)
    const int vsw  = (tid & 7) ^ ((tid >> 3) & 7);
    const int rowb = ((tid >> 3) << 1) | (vsw >> 2);   // 0..127
    const int cq8  = (vsw & 3) << 3;

    const unsigned short* pA0 = Xb + (size_t)(gm + rowb) * HDIM + cq8;
    const unsigned short* pA1 = pA0 + (size_t)128 * HDIM;
    auto wsrc = [&](int R) -> const unsigned short* {
        const unsigned short* base = ((R >> 4) & 1) ? Wu : Wg;
        int sr = ((R >> 5) << 4) | (R & 15);
        return base + (size_t)sr * HDIM + cq8;
    };
    const unsigned short* pB0 = wsrc(gn + rowb);
    const unsigned short* pB1 = wsrc(gn + rowb + 128);

    int aoff[8], boff[4];
    #pragma unroll
    for (int i = 0; i < 8; ++i) {
        int row = wm + i * 16 + tr;
        aoff[i] = ((row >> 1) << 7) | (((((row & 1) << 2) | quad) ^ ((row >> 1) & 7)) << 4);
    }
    #pragma unroll
    for (int i = 0; i < 4; ++i) {
        int row = wn + i * 16 + tr;
        boff[i] = ((row >> 1) << 7) | (((((row & 1) << 2) | quad) ^ ((row >> 1) & 7)) << 4);
    }

    f32x4 accL[4][4] = {};
    f32x4 accH[4][4] = {};
    bf16x8 af[4], bfv[4];

    auto stageA = [&](int slot, int kOff) {
        char* d = lds + (slot << 14) + (tid << 4);
        gld_lds16(pA0 + kOff, d);
        gld_lds16(pA1 + kOff, d + 8192);
    };
    auto stageB = [&](int slot, int kOff) {
        char* d = lds + 65536 + (slot << 14) + (tid << 4);
        gld_lds16(pB0 + kOff, d);
        gld_lds16(pB1 + kOff, d + 8192);
    };

    // prologue: stage tiles 0,1,2 (12 loads); vmcnt(8) -> tile0 complete
    stageA(0, 0);  stageB(0, 0);
    stageA(1, 32); stageB(1, 32);
    stageA(2, 64); stageB(2, 64);
    VMW(8); BARX();

    for (int t = 0; t < 32; ++t) {
        const int r  = t & 3;
        const int rn = (t + 3) & 3;
        const int kN = (t < 29 ? t + 3 : 31) << 5;   // clamped (dummy restage, never read)
        RD_A(r, 0); RD_B(r);
        stageA(rn, kN);
        MMA16(accL);
        RD_A(r, 4);
        stageB(rn, kN);
        MMA16(accH);
        VMW(8); BARX();
    }
    asm volatile("s_waitcnt vmcnt(0)" ::: "memory");  // drain DMA before block retires

    const size_t icb = (size_t)((gn + wn) >> 1) + tr;
    const int rbase = gm + wm + quad * 4;
    #pragma unroll
    for (int mi = 0; mi < 4; ++mi) {
        #pragma unroll
        for (int p = 0; p < 2; ++p) {
            #pragma unroll
            for (int r = 0; r < 4; ++r) {
                {
                    float g = accL[mi][2 * p][r], u2 = accL[mi][2 * p + 1][r];
                    float h = g / (1.0f + __expf(-g)) * u2;
                    Hb[(size_t)(rbase + mi * 16 + r) * IDIM + icb + 16 * p] = f2bf(h);
                }
                {
                    float g = accH[mi][2 * p][r], u2 = accH[mi][2 * p + 1][r];
                    float h = g / (1.0f + __expf(-g)) * u2;
                    Hb[(size_t)(rbase + 64 + mi * 16 + r) * IDIM + icb + 16 * p] = f2bf(h);
                }
            }
        }
    }
}

// ---------------- GEMM2 (down-proj): out += hbuf @ downb^T, 256x128 tile, BK=32 ring-4 ----------------
// Same 1-barrier-per-tile schedule; VMW(6) after MFMAs retires tile t+1's 3 stages.
// XCD map: each XCD owns 4 gm x 8 gn (16MB working set).
#define RD2_A(r) { const char* _p = lds + ((r) << 14); \
    _Pragma("unroll") \
    for (int _i = 0; _i < 8; ++_i) af[_i] = *(const bf16x8*)(_p + aoff[_i]); }

#define RD2_B(r) { const char* _p = lds + 65536 + ((r) << 13); \
    bfv[0] = *(const bf16x8*)(_p + boff[0]); \
    bfv[1] = *(const bf16x8*)(_p + boff[1]); }

#define MMA2() { __builtin_amdgcn_s_setprio(1); \
    _Pragma("unroll") \
    for (int _i = 0; _i < 8; ++_i) \
        _Pragma("unroll") \
        for (int _n = 0; _n < 2; ++_n) \
            acc[_i][_n] = __builtin_amdgcn_mfma_f32_16x16x32_bf16(af[_i], bfv[_n], acc[_i][_n], 0, 0, 0); \
    __builtin_amdgcn_s_setprio(0); }

__global__ __launch_bounds__(512, 2)
void gemm2_8ph(const unsigned short* __restrict__ A, const unsigned short* __restrict__ B,
               float* __restrict__ C) {
    __shared__ __align__(16) char lds[98304];
    const int K = IDIM, N = HDIM;
    const int tid  = threadIdx.x;
    const int lane = tid & 63;
    const int wid  = tid >> 6;
    const int quad = lane >> 4;
    const int tr   = lane & 15;
    const int wm   = (wid >> 2) << 7;   // 0 / 128
    const int wn   = (wid & 3) << 5;    // 0 / 32 / 64 / 96

    const int bid = blockIdx.x;
    const int u   = bid >> 3;
    const int gm  = (((bid & 7) << 2) | (u >> 3)) << 8;   // 0..7936
    const int gn  = (u & 7) << 7;                          // 0..896

    const int vsw  = (tid & 7) ^ ((tid >> 3) & 7);
    const int rowb = ((tid >> 3) << 1) | (vsw >> 2);   // 0..127
    const int cq8  = (vsw & 3) << 3;

    const unsigned short* pA0 = A + (size_t)(gm + rowb) * K + cq8;
    const unsigned short* pA1 = pA0 + (size_t)128 * K;
    const unsigned short* pB0 = B + (size_t)(gn + rowb) * K + cq8;

    int aoff[8], boff[2];
    #pragma unroll
    for (int i = 0; i < 8; ++i) {
        int row = wm + i * 16 + tr;
        aoff[i] = ((row >> 1) << 7) | (((((row & 1) << 2) | quad) ^ ((row >> 1) & 7)) << 4);
    }
    #pragma unroll
    for (int i = 0; i < 2; ++i) {
        int row = wn + i * 16 + tr;
        boff[i] = ((row >> 1) << 7) | (((((row & 1) << 2) | quad) ^ ((row >> 1) & 7)) << 4);
    }

    f32x4 acc[8][2] = {};
    bf16x8 af[8], bfv[2];

    auto stageA = [&](int slot, int kOff) {
        char* d = lds + (slot << 14) + (tid << 4);
        gld_lds16(pA0 + kOff, d);
        gld_lds16(pA1 + kOff, d + 8192);
    };
    auto stageB = [&](int slot, int kOff) {
        char* d = lds + 65536 + (slot << 13) + (tid << 4);
        gld_lds16(pB0 + kOff, d);
    };

    // prologue: stage tiles 0,1,2 (9 loads); vmcnt(6) -> tile0 complete
    stageA(0, 0);  stageB(0, 0);
    stageA(1, 32); stageB(1, 32);
    stageA(2, 64); stageB(2, 64);
    VMW(6); BARX();

    for (int t = 0; t < 128; ++t) {
        const int r  = t & 3;
        const int rn = (t + 3) & 3;
        const int kN = (t < 125 ? t + 3 : 127) << 5;
        RD2_A(r); RD2_B(r);
        stageA(rn, kN); stageB(rn, kN);
        MMA2();
        VMW(6); BARX();
    }
    asm volatile("s_waitcnt vmcnt(0)" ::: "memory");

    // epilogue: C += acc
    #pragma unroll
    for (int mi = 0; mi < 8; ++mi) {
        #pragma unroll
        for (int ni = 0; ni < 2; ++ni) {
            int col = gn + wn + ni * 16 + tr;
            #pragma unroll
            for (int r = 0; r < 4; ++r) {
                int row = gm + wm + mi * 16 + quad * 4 + r;
                size_t o = (size_t)row * N + col;
                C[o] += acc[mi][ni][r];
            }
        }
    }
}

// ---------------- batchnorm stats ----------------
__global__ void bn_stats(const float* __restrict__ gxy, float* __restrict__ sums, float* __restrict__ ssq) {
    const int j = threadIdx.x;
    const int b = blockIdx.x;
    float s = 0.f, q = 0.f;
    for (int r = 0; r < 32; ++r) {
        float v = gxy[(size_t)(b * 32 + r) * 256 + j];
        s += v; q += v * v;
    }
    atomicAdd(&sums[j], s);
    atomicAdd(&ssq[j], q);
}

// ---------------- routing: bn -> log_softmax -> top16 via candidate reduction ----------------
__global__ __launch_bounds__(256)
void routing_kernel(const float* __restrict__ gxy, const float* __restrict__ sums,
                    const float* __restrict__ ssq, int* __restrict__ oidx, float* __restrict__ owt) {
    const int lane = threadIdx.x & 63;
    const int t = blockIdx.x * 4 + (threadIdx.x >> 6);
    const float invT = 1.0f / (float)T_TOK;
    const float* g = gxy + (size_t)t * 256;

    float z[4];
    const int cols[4] = {lane, lane + 64, 128 + lane, 192 + lane};
    #pragma unroll
    for (int i = 0; i < 4; ++i) {
        int c = cols[i];
        float mu  = sums[c] * invT;
        float var = ssq[c] * invT - mu * mu;
        z[i] = (g[c] - mu) * rsqrtf(var + 1e-5f);
    }
    float mx = fmaxf(z[0], z[1]);
    float my = fmaxf(z[2], z[3]);
    #pragma unroll
    for (int m = 32; m >= 1; m >>= 1) {
        mx = fmaxf(mx, __shfl_xor(mx, m));
        my = fmaxf(my, __shfl_xor(my, m));
    }
    float sx = __expf(z[0] - mx) + __expf(z[1] - mx);
    float sy = __expf(z[2] - my) + __expf(z[3] - my);
    #pragma unroll
    for (int m = 32; m >= 1; m >>= 1) {
        sx += __shfl_xor(sx, m);
        sy += __shfl_xor(sy, m);
    }
    float lx0 = z[0] - (mx + __logf(sx)), lx1 = z[1] - (mx + __logf(sx));
    float ly0 = z[2] - (my + __logf(sy)), ly1 = z[3] - (my + __logf(sy));

    float aw = -INFINITY; int ai = 0;
    float bw = -INFINITY; int bi = 0;
    {
        float v0 = lx0, v1 = lx1;
        for (int i = 0; i < 16; ++i) {
            float v; int c;
            if (v0 >= v1) { v = v0; c = lane; } else { v = v1; c = lane + 64; }
            #pragma unroll
            for (int m = 32; m >= 1; m >>= 1) {
                float ov = __shfl_xor(v, m); int oc = __shfl_xor(c, m);
                if (ov > v || (ov == v && oc < c)) { v = ov; c = oc; }
            }
            if ((c & 63) == lane) { if (c < 64) v0 = -INFINITY; else v1 = -INFINITY; }
            if (lane == i) { aw = v; ai = c; }
        }
    }
    {
        float v0 = ly0, v1 = ly1;
        for (int i = 0; i < 16; ++i) {
            float v; int c;
            if (v0 >= v1) { v = v0; c = lane; } else { v = v1; c = lane + 64; }
            #pragma unroll
            for (int m = 32; m >= 1; m >>= 1) {
                float ov = __shfl_xor(v, m); int oc = __shfl_xor(c, m);
                if (ov > v || (ov == v && oc < c)) { v = ov; c = oc; }
            }
            if ((c & 63) == lane) { if (c < 64) v0 = -INFINITY; else v1 = -INFINITY; }
            if (lane == i) { bw = v; bi = c; }
        }
    }
    float cv[4];
    #pragma unroll
    for (int j = 0; j < 4; ++j) {
        int c = lane + 64 * j;
        cv[j] = __shfl(aw, c >> 4) + __shfl(bw, c & 15);
    }
    int myidx = 0; float myw = 0.f;
    for (int i = 0; i < 16; ++i) {
        float v = cv[0]; int c = lane;
        #pragma unroll
        for (int j = 1; j < 4; ++j) { int cc = lane + 64 * j; if (cv[j] > v) { v = cv[j]; c = cc; } }
        #pragma unroll
        for (int m = 32; m >= 1; m >>= 1) {
            float ov = __shfl_xor(v, m); int oc = __shfl_xor(c, m);
            if (ov > v || (ov == v && oc < c)) { v = ov; c = oc; }
        }
        #pragma unroll
        for (int j = 0; j < 4; ++j) if (c == lane + 64 * j) cv[j] = -INFINITY;
        int p = c >> 4, q = c & 15;
        int ex = __shfl(ai, p);
        int ey = __shfl(bi, q);
        if (lane == i) { myidx = ex * 128 + ey; myw = __expf(v); }
    }
    if (lane < 16) {
        oidx[t * TOPK + lane] = myidx;
        owt[t * TOPK + lane]  = myw;
    }
}

// ---------------- expert gather/combine (bf16 tables + bf16 x) ----------------
__global__ __launch_bounds__(256)
void expert_combine(const unsigned short* __restrict__ xb, const int* __restrict__ idx,
                    const float* __restrict__ wts, const unsigned short* __restrict__ ueb,
                    const unsigned short* __restrict__ deb, float* __restrict__ out) {
    const int t = blockIdx.x;
    const int tid = threadIdx.x;
    const int lane = tid & 63, wv = tid >> 6;
    __shared__ float part[TOPK * 4];
    __shared__ float sc[TOPK];
    ushort4 xv4 = ((const ushort4*)(xb + (size_t)t * HDIM))[tid];
    float x0 = bf2f(xv4.x), x1 = bf2f(xv4.y), x2 = bf2f(xv4.z), x3 = bf2f(xv4.w);
    int e[TOPK];
    #pragma unroll
    for (int k = 0; k < TOPK; ++k) e[k] = idx[t * TOPK + k];
    #pragma unroll
    for (int k = 0; k < TOPK; ++k) {
        ushort4 u4 = ((const ushort4*)(ueb + (size_t)e[k] * HDIM))[tid];
        float p = bf2f(u4.x) * x0 + bf2f(u4.y) * x1 + bf2f(u4.z) * x2 + bf2f(u4.w) * x3;
        #pragma unroll
        for (int m = 32; m >= 1; m >>= 1) p += __shfl_xor(p, m);
        if (lane == 0) part[k * 4 + wv] = p;
    }
    __syncthreads();
    if (tid < TOPK) {
        float s = part[tid * 4] + part[tid * 4 + 1] + part[tid * 4 + 2] + part[tid * 4 + 3];
        sc[tid] = s * wts[t * TOPK + tid];
    }
    __syncthreads();
    float4 acc = {0.f, 0.f, 0.f, 0.f};
    #pragma unroll
    for (int k = 0; k < TOPK; ++k) {
        float s = sc[k];
        ushort4 d4 = ((const ushort4*)(deb + (size_t)e[k] * HDIM))[tid];
        acc.x += s * bf2f(d4.x); acc.y += s * bf2f(d4.y);
        acc.z += s * bf2f(d4.z); acc.w += s * bf2f(d4.w);
    }
    ((float4*)(out + (size_t)t * HDIM))[tid] = acc;
}

extern "C" void kernel_launch(void* const* d_in, const int* in_sizes, int n_in,
                              void* d_out, int out_size, void* d_ws, size_t ws_size,
                              hipStream_t stream) {
    const float* x  = (const float*)d_in[0];
    const float* gw = (const float*)d_in[1];
    const float* uw = (const float*)d_in[2];
    const float* dw = (const float*)d_in[3];
    const float* wx = (const float*)d_in[4];
    const float* wy = (const float*)d_in[5];
    const float* ue = (const float*)d_in[6];
    const float* de = (const float*)d_in[7];
    float* out = (float*)d_out;

    char* ws = (char*)d_ws;
    size_t o = 0;
    auto alloc = [&](size_t bytes) { void* p = ws + o; o += (bytes + 255) & ~(size_t)255; return p; };
    unsigned short* xb    = (unsigned short*)alloc((size_t)T_TOK * HDIM * 2);
    unsigned short* gateb = (unsigned short*)alloc((size_t)IDIM * HDIM * 2);
    unsigned short* upb   = (unsigned short*)alloc((size_t)IDIM * HDIM * 2);
    unsigned short* downb = (unsigned short*)alloc((size_t)HDIM * IDIM * 2);
    unsigned short* wrb   = (unsigned short*)alloc((size_t)256 * HDIM * 2);
    unsigned short* ueb   = (unsigned short*)alloc((size_t)16384 * HDIM * 2);
    unsigned short* deb   = (unsigned short*)alloc((size_t)16384 * HDIM * 2);
    unsigned short* hbuf  = (unsigned short*)alloc((size_t)T_TOK * IDIM * 2);
    float* gxy  = (float*)alloc((size_t)T_TOK * 256 * 4);
    float* sums = (float*)alloc(256 * 4);
    float* ssq  = (float*)alloc(256 * 4);
    int*   idxs = (int*)alloc((size_t)T_TOK * TOPK * 4);
    float* wts  = (float*)alloc((size_t)T_TOK * TOPK * 4);

    // merged converts (8 segments)
    CvtSegs segs;
    const float* srcs[8] = {x, gw, uw, dw, wx, wy, ue, de};
    unsigned short* dsts[8] = {xb, gateb, upb, downb, wrb, wrb + SDIM * HDIM, ueb, deb};
    const int cnt4[8] = {T_TOK * HDIM / 4, IDIM * HDIM / 4, IDIM * HDIM / 4, IDIM * HDIM / 4,
                         SDIM * HDIM / 4, SDIM * HDIM / 4, 16384 * HDIM / 4, 16384 * HDIM / 4};
    int acc = 0;
    for (int i = 0; i < 8; ++i) {
        segs.src[i] = (const float4*)srcs[i];
        segs.dst[i] = (ushort4*)dsts[i];
        acc += cnt4[i];
        segs.end[i] = acc;
    }
    cvt_all_kernel<<<(acc + 255) / 256, 256, 0, stream>>>(segs);

    // router logits: gxy[T,256] = xb @ wrb^T
    hipMemsetAsync(sums, 0, 2 * 256 * 4, stream);  // sums+ssq contiguous
    gemm_bt<0><<<dim3(T_TOK / 128, 256 / 128), 256, 0, stream>>>(xb, wrb, gxy, T_TOK, 256, HDIM);
    bn_stats<<<256, 256, 0, stream>>>(gxy, sums, ssq);
    routing_kernel<<<T_TOK / 4, 256, 0, stream>>>(gxy, sums, ssq, idxs, wts);

    // expert branch writes out fully
    expert_combine<<<T_TOK, 256, 0, stream>>>(xb, idxs, wts, ueb, deb, out);

    // MLP branch: ring-4 fused gate/up GEMM, then ring-4 down-proj accumulate
    gemm1_8ph<<<1024, 512, 0, stream>>>(xb, gateb, upb, hbuf);
    gemm2_8ph<<<256, 512, 0, stream>>>(hbuf, downb, out);
}

// Round 7
// 641.630 us; speedup vs baseline: 1.0005x; 1.0005x over previous
//
#include <hip/hip_runtime.h>
#include <hip/hip_bf16.h>
#include <math.h>

#define T_TOK 8192
#define HDIM  1024
#define IDIM  4096
#define SDIM  128
#define TOPK  16

typedef __bf16 bf16x8 __attribute__((ext_vector_type(8)));
typedef float  f32x4  __attribute__((ext_vector_type(4)));

__device__ __forceinline__ unsigned short f2bf(float f) {
    union { float f; unsigned u; } a; a.f = f;
    unsigned r = a.u + 0x7fffu + ((a.u >> 16) & 1u);
    return (unsigned short)(r >> 16);
}
__device__ __forceinline__ float bf2f(unsigned short b) {
    union { unsigned u; float f; } a; a.u = ((unsigned)b) << 16;
    return a.f;
}

__device__ __forceinline__ void gld_lds16(const void* g, void* l) {
    __builtin_amdgcn_global_load_lds(
        (__attribute__((address_space(1))) void*)g,
        (__attribute__((address_space(3))) void*)l,
        16, 0, 0);
}

// ---------------- merged fp32 -> bf16 convert over 8 segments ----------------
struct CvtSegs {
    const float4* src[8];
    ushort4*      dst[8];
    int           end[8];   // prefix-sum of float4 counts
};

__global__ __launch_bounds__(256)
void cvt_all_kernel(CvtSegs segs) {
    int i = blockIdx.x * 256 + threadIdx.x;
    if (i >= segs.end[7]) return;
    int s = 0;
    #pragma unroll
    for (int k = 0; k < 7; ++k) s += (i >= segs.end[k]) ? 1 : 0;
    int base = (s == 0) ? 0 : segs.end[s - 1];
    int j = i - base;
    float4 v = segs.src[s][j];
    ushort4 o;
    o.x = f2bf(v.x); o.y = f2bf(v.y); o.z = f2bf(v.z); o.w = f2bf(v.w);
    segs.dst[s][j] = o;
}

// ---------------- generic C = A * B^T (bf16 in, fp32 out), 128x128 tile ----------------
// (kept only for the small router GEMM)
template<int ADD>
__global__ __launch_bounds__(256)
void gemm_bt(const unsigned short* __restrict__ A, const unsigned short* __restrict__ B,
             float* __restrict__ C, int M, int N, int K) {
    __shared__ unsigned short As[4096];  // [kc=4][m=128][8] bf16
    __shared__ unsigned short Bs[4096];  // [kc=4][n=128][8]
    const int tid  = threadIdx.x;
    const int lane = tid & 63;
    const int wave = tid >> 6;
    const int tm = blockIdx.x * 128;
    const int tn = blockIdx.y * 128;
    const int wm = (wave & 1) * 64;
    const int wn = (wave >> 1) * 64;
    const int quad = lane >> 4;
    const int tr   = lane & 15;

    f32x4 acc[4][4] = {};
    bf16x8 af[4], bfr[4];

    const int ua0 = tid,        am0 = ua0 & 127, ak0 = ua0 >> 7;
    const int ua1 = tid + 256,  am1 = ua1 & 127, ak1 = ua1 >> 7;

    auto issue = [&](int kt) {
        gld_lds16(A + (size_t)(tm + am0) * K + kt + ak0 * 8, &As[ua0 * 8]);
        gld_lds16(A + (size_t)(tm + am1) * K + kt + ak1 * 8, &As[ua1 * 8]);
        gld_lds16(B + (size_t)(tn + am0) * K + kt + ak0 * 8, &Bs[ua0 * 8]);
        gld_lds16(B + (size_t)(tn + am1) * K + kt + ak1 * 8, &Bs[ua1 * 8]);
    };
    auto rdfrags = [&]() {
        #pragma unroll
        for (int mi = 0; mi < 4; ++mi)
            af[mi] = *(const bf16x8*)&As[(quad * 128 + wm + mi * 16 + tr) * 8];
        #pragma unroll
        for (int ni = 0; ni < 4; ++ni)
            bfr[ni] = *(const bf16x8*)&Bs[(quad * 128 + wn + ni * 16 + tr) * 8];
    };
    auto mfmas = [&]() {
        #pragma unroll
        for (int mi = 0; mi < 4; ++mi)
            #pragma unroll
            for (int ni = 0; ni < 4; ++ni)
                acc[mi][ni] = __builtin_amdgcn_mfma_f32_16x16x32_bf16(af[mi], bfr[ni], acc[mi][ni], 0, 0, 0);
    };

    issue(0);
    asm volatile("s_waitcnt vmcnt(0)" ::: "memory");
    __syncthreads();
    rdfrags();
    for (int kt = 32; kt < K; kt += 32) {
        __syncthreads();
        issue(kt);
        mfmas();
        asm volatile("s_waitcnt vmcnt(0)" ::: "memory");
        __syncthreads();
        rdfrags();
    }
    mfmas();

    #pragma unroll
    for (int mi = 0; mi < 4; ++mi) {
        #pragma unroll
        for (int ni = 0; ni < 4; ++ni) {
            int col = tn + wn + ni * 16 + tr;
            #pragma unroll
            for (int r = 0; r < 4; ++r) {
                int row = tm + wm + mi * 16 + quad * 4 + r;
                size_t o = (size_t)row * N + col;
                float v = acc[mi][ni][r];
                if (ADD) v += C[o];
                C[o] = v;
            }
        }
    }
}

// common swizzle pieces for the ring kernels:
//   slotoff(row,cq) = (row>>1)*128 + ((((row&1)<<2)|cq) ^ ((row>>1)&7))*16
#define BARX() asm volatile("s_barrier" ::: "memory")
#define VMW(n) asm volatile("s_waitcnt vmcnt(" #n ")" ::: "memory")

// ---------------- fused GEMM1, 256x256 tile, BK=32 ring-4, reg-double-buffered frags --------
// h = silu(x @ Wg^T) * (x @ Wu^T), bf16 out. Virtual interleaved Wcat as before.
// Software pipeline: during tile t's 32 MFMAs (frag set CUR, read during tile t-1), issue the
// 12 ds_read_b128 for tile t+1 into set NXT + the 4 gld_lds for tile t+3. Counted lgkmcnt ->
// LDS pipe runs under the MFMA burst within each wave.
// VMCNT LEDGER (4 loads/stage, stage for slot t+3 issued during tile t): end-of-tile-t VMW(4)
// leaves ONLY slot t+4's stage outstanding => slot t+3 ... i.e. at start of tile t, slots
// <= t+1 are complete, so the prefetch-read of slot t+1 during tile t is race-free.
// (Round-6 bug: VMW(8) left slot t+1 in flight -> stale reads, absmax 0.75.)
// Slot overwrite (t+3 == t-1 mod 4) is >=2 barriers after that slot's last reader.
// XCD map: each XCD owns 4 gm (2MB A, L2-resident) x all 32 gn (B streams).
#define RDT1(AF, BV, r) { const char* _pa = lds + ((r) << 14); \
    const char* _pb = lds + 65536 + ((r) << 14); \
    _Pragma("unroll") \
    for (int _i = 0; _i < 8; ++_i) AF[_i] = *(const bf16x8*)(_pa + aoff[_i]); \
    _Pragma("unroll") \
    for (int _n = 0; _n < 4; ++_n) BV[_n] = *(const bf16x8*)(_pb + boff[_n]); }

#define MMAT1(AF, BV) { __builtin_amdgcn_s_setprio(1); \
    _Pragma("unroll") \
    for (int _i = 0; _i < 4; ++_i) \
        _Pragma("unroll") \
        for (int _n = 0; _n < 4; ++_n) \
            accL[_i][_n] = __builtin_amdgcn_mfma_f32_16x16x32_bf16(AF[_i], BV[_n], accL[_i][_n], 0, 0, 0); \
    _Pragma("unroll") \
    for (int _i = 0; _i < 4; ++_i) \
        _Pragma("unroll") \
        for (int _n = 0; _n < 4; ++_n) \
            accH[_i][_n] = __builtin_amdgcn_mfma_f32_16x16x32_bf16(AF[_i + 4], BV[_n], accH[_i][_n], 0, 0, 0); \
    __builtin_amdgcn_s_setprio(0); }

__global__ __launch_bounds__(512, 2)
void gemm1_8ph(const unsigned short* __restrict__ Xb, const unsigned short* __restrict__ Wg,
               const unsigned short* __restrict__ Wu, unsigned short* __restrict__ Hb) {
    __shared__ __align__(16) char lds[131072];
    const int tid  = threadIdx.x;
    const int lane = tid & 63;
    const int wid  = tid >> 6;
    const int quad = lane >> 4;
    const int tr   = lane & 15;
    const int wm   = (wid >> 2) << 7;   // 0 / 128
    const int wn   = (wid & 3) << 6;    // 0 / 64 / 128 / 192

    // XCD map: xcd = bid&7 owns gm in {xcd*4 .. xcd*4+3} (A 2MB, L2-resident), gn sweeps 0..31.
    const int bid = blockIdx.x;
    const int u   = bid >> 3;
    const int gm  = (((bid & 7) << 2) | (u & 3)) << 8;
    const int gn  = (u >> 2) << 8;

    // staging thread map (inverse of the LDS swizzle, so gld_lds dest stays linear)
    const int vsw  = (tid & 7) ^ ((tid >> 3) & 7);
    const int rowb = ((tid >> 3) << 1) | (vsw >> 2);   // 0..127
    const int cq8  = (vsw & 3) << 3;

    const unsigned short* pA0 = Xb + (size_t)(gm + rowb) * HDIM + cq8;
    const unsigned short* pA1 = pA0 + (size_t)128 * HDIM;
    auto wsrc = [&](int R) -> const unsigned short* {
        const unsigned short* base = ((R >> 4) & 1) ? Wu : Wg;
        int sr = ((R >> 5) << 4) | (R & 15);
        return base + (size_t)sr * HDIM + cq8;
    };
    const unsigned short* pB0 = wsrc(gn + rowb);
    const unsigned short* pB1 = wsrc(gn + rowb + 128);

    int aoff[8], boff[4];
    #pragma unroll
    for (int i = 0; i < 8; ++i) {
        int row = wm + i * 16 + tr;
        aoff[i] = ((row >> 1) << 7) | (((((row & 1) << 2) | quad) ^ ((row >> 1) & 7)) << 4);
    }
    #pragma unroll
    for (int i = 0; i < 4; ++i) {
        int row = wn + i * 16 + tr;
        boff[i] = ((row >> 1) << 7) | (((((row & 1) << 2) | quad) ^ ((row >> 1) & 7)) << 4);
    }

    f32x4 accL[4][4] = {};
    f32x4 accH[4][4] = {};
    bf16x8 afA[8], bvA[4], afB[8], bvB[4];

    auto stageAB = [&](int slot, int kOff) {
        char* da = lds + (slot << 14) + (tid << 4);
        char* db = lds + 65536 + (slot << 14) + (tid << 4);
        gld_lds16(pA0 + kOff, da);
        gld_lds16(pA1 + kOff, da + 8192);
        gld_lds16(pB0 + kOff, db);
        gld_lds16(pB1 + kOff, db + 8192);
    };

    // prologue: stage tiles 0,1,2 (12 loads); vmcnt(4) -> slots 0 AND 1 complete
    stageAB(0, 0);
    stageAB(1, 32);
    stageAB(2, 64);
    VMW(4); BARX();
    RDT1(afA, bvA, 0);

    for (int tt = 0; tt < 16; ++tt) {
        const int t0 = tt * 2, t1 = t0 + 1;
        // ---- tile t0: prefetch frags t1 -> set B, stage slot t0+3, MFMA on set A
        RDT1(afB, bvB, t1 & 3);
        { int ts = t0 + 3; stageAB(ts & 3, (ts <= 31 ? ts : 31) << 5); }
        __builtin_amdgcn_sched_barrier(0);
        MMAT1(afA, bvA);
        VMW(4); BARX();
        // ---- tile t1: prefetch frags t1+1 -> set A, stage slot t1+3, MFMA on set B
        RDT1(afA, bvA, (t1 + 1) & 3);   // at tt=15 this is a dummy in-bounds read (unused)
        { int ts = t1 + 3; stageAB(ts & 3, (ts <= 31 ? ts : 31) << 5); }
        __builtin_amdgcn_sched_barrier(0);
        MMAT1(afB, bvB);
        VMW(4); BARX();
    }
    asm volatile("s_waitcnt vmcnt(0)" ::: "memory");  // drain DMA before block retires

    const size_t icb = (size_t)((gn + wn) >> 1) + tr;
    const int rbase = gm + wm + quad * 4;
    #pragma unroll
    for (int mi = 0; mi < 4; ++mi) {
        #pragma unroll
        for (int p = 0; p < 2; ++p) {
            #pragma unroll
            for (int r = 0; r < 4; ++r) {
                {
                    float g = accL[mi][2 * p][r], u2 = accL[mi][2 * p + 1][r];
                    float h = g / (1.0f + __expf(-g)) * u2;
                    Hb[(size_t)(rbase + mi * 16 + r) * IDIM + icb + 16 * p] = f2bf(h);
                }
                {
                    float g = accH[mi][2 * p][r], u2 = accH[mi][2 * p + 1][r];
                    float h = g / (1.0f + __expf(-g)) * u2;
                    Hb[(size_t)(rbase + 64 + mi * 16 + r) * IDIM + icb + 16 * p] = f2bf(h);
                }
            }
        }
    }
}

// ---------------- GEMM2 (down-proj): out += hbuf @ downb^T, 256x128 tile, BK=32 ring-4 ------
// Wave grid 4M x 2N (wave tile 64x64): 8 ds_read_b128/wave/tile (balanced vs matrix pipe).
// Same reg-double-buffered frag pipeline as gemm1. VMCNT LEDGER (3 loads/stage): end-of-tile
// VMW(3) leaves only the current tile's stage outstanding -> prefetched slot complete.
// XCD map: each XCD owns 4 gm x 8 gn (16MB working set).
#define RDT2(AF, BV, r) { const char* _pa = lds + ((r) << 14); \
    const char* _pb = lds + 65536 + ((r) << 13); \
    _Pragma("unroll") \
    for (int _i = 0; _i < 4; ++_i) AF[_i] = *(const bf16x8*)(_pa + aoff[_i]); \
    _Pragma("unroll") \
    for (int _n = 0; _n < 4; ++_n) BV[_n] = *(const bf16x8*)(_pb + boff[_n]); }

#define MMAT2(AF, BV) { __builtin_amdgcn_s_setprio(1); \
    _Pragma("unroll") \
    for (int _i = 0; _i < 4; ++_i) \
        _Pragma("unroll") \
        for (int _n = 0; _n < 4; ++_n) \
            acc[_i][_n] = __builtin_amdgcn_mfma_f32_16x16x32_bf16(AF[_i], BV[_n], acc[_i][_n], 0, 0, 0); \
    __builtin_amdgcn_s_setprio(0); }

__global__ __launch_bounds__(512, 2)
void gemm2_8ph(const unsigned short* __restrict__ A, const unsigned short* __restrict__ B,
               float* __restrict__ C) {
    __shared__ __align__(16) char lds[98304];
    const int K = IDIM, N = HDIM;
    const int tid  = threadIdx.x;
    const int lane = tid & 63;
    const int wid  = tid >> 6;
    const int quad = lane >> 4;
    const int tr   = lane & 15;
    const int wm   = (wid >> 1) << 6;   // 0 / 64 / 128 / 192
    const int wn   = (wid & 1) << 6;    // 0 / 64

    const int bid = blockIdx.x;
    const int u   = bid >> 3;
    const int gm  = (((bid & 7) << 2) | (u >> 3)) << 8;   // 0..7936
    const int gn  = (u & 7) << 7;                          // 0..896

    const int vsw  = (tid & 7) ^ ((tid >> 3) & 7);
    const int rowb = ((tid >> 3) << 1) | (vsw >> 2);   // 0..127
    const int cq8  = (vsw & 3) << 3;

    const unsigned short* pA0 = A + (size_t)(gm + rowb) * K + cq8;
    const unsigned short* pA1 = pA0 + (size_t)128 * K;
    const unsigned short* pB0 = B + (size_t)(gn + rowb) * K + cq8;

    int aoff[4], boff[4];
    #pragma unroll
    for (int i = 0; i < 4; ++i) {
        int row = wm + i * 16 + tr;
        aoff[i] = ((row >> 1) << 7) | (((((row & 1) << 2) | quad) ^ ((row >> 1) & 7)) << 4);
    }
    #pragma unroll
    for (int i = 0; i < 4; ++i) {
        int row = wn + i * 16 + tr;
        boff[i] = ((row >> 1) << 7) | (((((row & 1) << 2) | quad) ^ ((row >> 1) & 7)) << 4);
    }

    f32x4 acc[4][4] = {};
    bf16x8 afA[4], bvA[4], afB[4], bvB[4];

    auto stageAB = [&](int slot, int kOff) {
        char* da = lds + (slot << 14) + (tid << 4);
        char* db = lds + 65536 + (slot << 13) + (tid << 4);
        gld_lds16(pA0 + kOff, da);
        gld_lds16(pA1 + kOff, da + 8192);
        gld_lds16(pB0 + kOff, db);
    };

    // prologue: stage tiles 0,1,2 (9 loads); vmcnt(3) -> slots 0 AND 1 complete
    stageAB(0, 0);
    stageAB(1, 32);
    stageAB(2, 64);
    VMW(3); BARX();
    RDT2(afA, bvA, 0);

    for (int tt = 0; tt < 64; ++tt) {
        const int t0 = tt * 2, t1 = t0 + 1;
        // ---- tile t0
        RDT2(afB, bvB, t1 & 3);
        { int ts = t0 + 3; stageAB(ts & 3, (ts <= 127 ? ts : 127) << 5); }
        __builtin_amdgcn_sched_barrier(0);
        MMAT2(afA, bvA);
        VMW(3); BARX();
        // ---- tile t1
        RDT2(afA, bvA, (t1 + 1) & 3);   // dummy in-bounds at tt=63 (unused)
        { int ts = t1 + 3; stageAB(ts & 3, (ts <= 127 ? ts : 127) << 5); }
        __builtin_amdgcn_sched_barrier(0);
        MMAT2(afB, bvB);
        VMW(3); BARX();
    }
    asm volatile("s_waitcnt vmcnt(0)" ::: "memory");

    // epilogue: C += acc
    #pragma unroll
    for (int mi = 0; mi < 4; ++mi) {
        #pragma unroll
        for (int ni = 0; ni < 4; ++ni) {
            int col = gn + wn + ni * 16 + tr;
            #pragma unroll
            for (int r = 0; r < 4; ++r) {
                int row = gm + wm + mi * 16 + quad * 4 + r;
                size_t o = (size_t)row * N + col;
                C[o] += acc[mi][ni][r];
            }
        }
    }
}

// ---------------- batchnorm stats ----------------
__global__ void bn_stats(const float* __restrict__ gxy, float* __restrict__ sums, float* __restrict__ ssq) {
    const int j = threadIdx.x;
    const int b = blockIdx.x;
    float s = 0.f, q = 0.f;
    for (int r = 0; r < 32; ++r) {
        float v = gxy[(size_t)(b * 32 + r) * 256 + j];
        s += v; q += v * v;
    }
    atomicAdd(&sums[j], s);
    atomicAdd(&ssq[j], q);
}

// ---------------- routing: bn -> log_softmax -> top16 via candidate reduction ----------------
__global__ __launch_bounds__(256)
void routing_kernel(const float* __restrict__ gxy, const float* __restrict__ sums,
                    const float* __restrict__ ssq, int* __restrict__ oidx, float* __restrict__ owt) {
    const int lane = threadIdx.x & 63;
    const int t = blockIdx.x * 4 + (threadIdx.x >> 6);
    const float invT = 1.0f / (float)T_TOK;
    const float* g = gxy + (size_t)t * 256;

    float z[4];
    const int cols[4] = {lane, lane + 64, 128 + lane, 192 + lane};
    #pragma unroll
    for (int i = 0; i < 4; ++i) {
        int c = cols[i];
        float mu  = sums[c] * invT;
        float var = ssq[c] * invT - mu * mu;
        z[i] = (g[c] - mu) * rsqrtf(var + 1e-5f);
    }
    float mx = fmaxf(z[0], z[1]);
    float my = fmaxf(z[2], z[3]);
    #pragma unroll
    for (int m = 32; m >= 1; m >>= 1) {
        mx = fmaxf(mx, __shfl_xor(mx, m));
        my = fmaxf(my, __shfl_xor(my, m));
    }
    float sx = __expf(z[0] - mx) + __expf(z[1] - mx);
    float sy = __expf(z[2] - my) + __expf(z[3] - my);
    #pragma unroll
    for (int m = 32; m >= 1; m >>= 1) {
        sx += __shfl_xor(sx, m);
        sy += __shfl_xor(sy, m);
    }
    float lx0 = z[0] - (mx + __logf(sx)), lx1 = z[1] - (mx + __logf(sx));
    float ly0 = z[2] - (my + __logf(sy)), ly1 = z[3] - (my + __logf(sy));

    float aw = -INFINITY; int ai = 0;
    float bw = -INFINITY; int bi = 0;
    {
        float v0 = lx0, v1 = lx1;
        for (int i = 0; i < 16; ++i) {
            float v; int c;
            if (v0 >= v1) { v = v0; c = lane; } else { v = v1; c = lane + 64; }
            #pragma unroll
            for (int m = 32; m >= 1; m >>= 1) {
                float ov = __shfl_xor(v, m); int oc = __shfl_xor(c, m);
                if (ov > v || (ov == v && oc < c)) { v = ov; c = oc; }
            }
            if ((c & 63) == lane) { if (c < 64) v0 = -INFINITY; else v1 = -INFINITY; }
            if (lane == i) { aw = v; ai = c; }
        }
    }
    {
        float v0 = ly0, v1 = ly1;
        for (int i = 0; i < 16; ++i) {
            float v; int c;
            if (v0 >= v1) { v = v0; c = lane; } else { v = v1; c = lane + 64; }
            #pragma unroll
            for (int m = 32; m >= 1; m >>= 1) {
                float ov = __shfl_xor(v, m); int oc = __shfl_xor(c, m);
                if (ov > v || (ov == v && oc < c)) { v = ov; c = oc; }
            }
            if ((c & 63) == lane) { if (c < 64) v0 = -INFINITY; else v1 = -INFINITY; }
            if (lane == i) { bw = v; bi = c; }
        }
    }
    float cv[4];
    #pragma unroll
    for (int j = 0; j < 4; ++j) {
        int c = lane + 64 * j;
        cv[j] = __shfl(aw, c >> 4) + __shfl(bw, c & 15);
    }
    int myidx = 0; float myw = 0.f;
    for (int i = 0; i < 16; ++i) {
        float v = cv[0]; int c = lane;
        #pragma unroll
        for (int j = 1; j < 4; ++j) { int cc = lane + 64 * j; if (cv[j] > v) { v = cv[j]; c = cc; } }
        #pragma unroll
        for (int m = 32; m >= 1; m >>= 1) {
            float ov = __shfl_xor(v, m); int oc = __shfl_xor(c, m);
            if (ov > v || (ov == v && oc < c)) { v = ov; c = oc; }
        }
        #pragma unroll
        for (int j = 0; j < 4; ++j) if (c == lane + 64 * j) cv[j] = -INFINITY;
        int p = c >> 4, q = c & 15;
        int ex = __shfl(ai, p);
        int ey = __shfl(bi, q);
        if (lane == i) { myidx = ex * 128 + ey; myw = __expf(v); }
    }
    if (lane < 16) {
        oidx[t * TOPK + lane] = myidx;
        owt[t * TOPK + lane]  = myw;
    }
}

// ---------------- expert gather/combine (bf16 tables + bf16 x) ----------------
__global__ __launch_bounds__(256)
void expert_combine(const unsigned short* __restrict__ xb, const int* __restrict__ idx,
                    const float* __restrict__ wts, const unsigned short* __restrict__ ueb,
                    const unsigned short* __restrict__ deb, float* __restrict__ out) {
    const int t = blockIdx.x;
    const int tid = threadIdx.x;
    const int lane = tid & 63, wv = tid >> 6;
    __shared__ float part[TOPK * 4];
    __shared__ float sc[TOPK];
    ushort4 xv4 = ((const ushort4*)(xb + (size_t)t * HDIM))[tid];
    float x0 = bf2f(xv4.x), x1 = bf2f(xv4.y), x2 = bf2f(xv4.z), x3 = bf2f(xv4.w);
    int e[TOPK];
    #pragma unroll
    for (int k = 0; k < TOPK; ++k) e[k] = idx[t * TOPK + k];
    #pragma unroll
    for (int k = 0; k < TOPK; ++k) {
        ushort4 u4 = ((const ushort4*)(ueb + (size_t)e[k] * HDIM))[tid];
        float p = bf2f(u4.x) * x0 + bf2f(u4.y) * x1 + bf2f(u4.z) * x2 + bf2f(u4.w) * x3;
        #pragma unroll
        for (int m = 32; m >= 1; m >>= 1) p += __shfl_xor(p, m);
        if (lane == 0) part[k * 4 + wv] = p;
    }
    __syncthreads();
    if (tid < TOPK) {
        float s = part[tid * 4] + part[tid * 4 + 1] + part[tid * 4 + 2] + part[tid * 4 + 3];
        sc[tid] = s * wts[t * TOPK + tid];
    }
    __syncthreads();
    float4 acc = {0.f, 0.f, 0.f, 0.f};
    #pragma unroll
    for (int k = 0; k < TOPK; ++k) {
        float s = sc[k];
        ushort4 d4 = ((const ushort4*)(deb + (size_t)e[k] * HDIM))[tid];
        acc.x += s * bf2f(d4.x); acc.y += s * bf2f(d4.y);
        acc.z += s * bf2f(d4.z); acc.w += s * bf2f(d4.w);
    }
    ((float4*)(out + (size_t)t * HDIM))[tid] = acc;
}

extern "C" void kernel_launch(void* const* d_in, const int* in_sizes, int n_in,
                              void* d_out, int out_size, void* d_ws, size_t ws_size,
                              hipStream_t stream) {
    const float* x  = (const float*)d_in[0];
    const float* gw = (const float*)d_in[1];
    const float* uw = (const float*)d_in[2];
    const float* dw = (const float*)d_in[3];
    const float* wx = (const float*)d_in[4];
    const float* wy = (const float*)d_in[5];
    const float* ue = (const float*)d_in[6];
    const float* de = (const float*)d_in[7];
    float* out = (float*)d_out;

    char* ws = (char*)d_ws;
    size_t o = 0;
    auto alloc = [&](size_t bytes) { void* p = ws + o; o += (bytes + 255) & ~(size_t)255; return p; };
    unsigned short* xb    = (unsigned short*)alloc((size_t)T_TOK * HDIM * 2);
    unsigned short* gateb = (unsigned short*)alloc((size_t)IDIM * HDIM * 2);
    unsigned short* upb   = (unsigned short*)alloc((size_t)IDIM * HDIM * 2);
    unsigned short* downb = (unsigned short*)alloc((size_t)HDIM * IDIM * 2);
    unsigned short* wrb   = (unsigned short*)alloc((size_t)256 * HDIM * 2);
    unsigned short* ueb   = (unsigned short*)alloc((size_t)16384 * HDIM * 2);
    unsigned short* deb   = (unsigned short*)alloc((size_t)16384 * HDIM * 2);
    unsigned short* hbuf  = (unsigned short*)alloc((size_t)T_TOK * IDIM * 2);
    float* gxy  = (float*)alloc((size_t)T_TOK * 256 * 4);
    float* sums = (float*)alloc(256 * 4);
    float* ssq  = (float*)alloc(256 * 4);
    int*   idxs = (int*)alloc((size_t)T_TOK * TOPK * 4);
    float* wts  = (float*)alloc((size_t)T_TOK * TOPK * 4);

    // merged converts (8 segments)
    CvtSegs segs;
    const float* srcs[8] = {x, gw, uw, dw, wx, wy, ue, de};
    unsigned short* dsts[8] = {xb, gateb, upb, downb, wrb, wrb + SDIM * HDIM, ueb, deb};
    const int cnt4[8] = {T_TOK * HDIM / 4, IDIM * HDIM / 4, IDIM * HDIM / 4, IDIM * HDIM / 4,
                         SDIM * HDIM / 4, SDIM * HDIM / 4, 16384 * HDIM / 4, 16384 * HDIM / 4};
    int acc = 0;
    for (int i = 0; i < 8; ++i) {
        segs.src[i] = (const float4*)srcs[i];
        segs.dst[i] = (ushort4*)dsts[i];
        acc += cnt4[i];
        segs.end[i] = acc;
    }
    cvt_all_kernel<<<(acc + 255) / 256, 256, 0, stream>>>(segs);

    // router logits: gxy[T,256] = xb @ wrb^T
    hipMemsetAsync(sums, 0, 2 * 256 * 4, stream);  // sums+ssq contiguous
    gemm_bt<0><<<dim3(T_TOK / 128, 256 / 128), 256, 0, stream>>>(xb, wrb, gxy, T_TOK, 256, HDIM);
    bn_stats<<<256, 256, 0, stream>>>(gxy, sums, ssq);
    routing_kernel<<<T_TOK / 4, 256, 0, stream>>>(gxy, sums, ssq, idxs, wts);

    // expert branch writes out fully
    expert_combine<<<T_TOK, 256, 0, stream>>>(xb, idxs, wts, ueb, deb, out);

    // MLP branch: reg-pipelined ring-4 GEMMs
    gemm1_8ph<<<1024, 512, 0, stream>>>(xb, gateb, upb, hbuf);
    gemm2_8ph<<<256, 512, 0, stream>>>(hbuf, downb, out);
}

// Round 8
// 637.798 us; speedup vs baseline: 1.0065x; 1.0060x over previous
//
#include <hip/hip_runtime.h>
#include <hip/hip_bf16.h>
#include <math.h>

#define T_TOK 8192
#define HDIM  1024
#define IDIM  4096
#define SDIM  128
#define TOPK  16

typedef __bf16 bf16x8 __attribute__((ext_vector_type(8)));
typedef float  f32x4  __attribute__((ext_vector_type(4)));

__device__ __forceinline__ unsigned short f2bf(float f) {
    union { float f; unsigned u; } a; a.f = f;
    unsigned r = a.u + 0x7fffu + ((a.u >> 16) & 1u);
    return (unsigned short)(r >> 16);
}
__device__ __forceinline__ float bf2f(unsigned short b) {
    union { unsigned u; float f; } a; a.u = ((unsigned)b) << 16;
    return a.f;
}

__device__ __forceinline__ void gld_lds16(const void* g, void* l) {
    __builtin_amdgcn_global_load_lds(
        (__attribute__((address_space(1))) void*)g,
        (__attribute__((address_space(3))) void*)l,
        16, 0, 0);
}

// ---------------- merged fp32 -> bf16 convert over 8 segments ----------------
struct CvtSegs {
    const float4* src[8];
    ushort4*      dst[8];
    int           end[8];   // prefix-sum of float4 counts
};

__global__ __launch_bounds__(256)
void cvt_all_kernel(CvtSegs segs) {
    int i = blockIdx.x * 256 + threadIdx.x;
    if (i >= segs.end[7]) return;
    int s = 0;
    #pragma unroll
    for (int k = 0; k < 7; ++k) s += (i >= segs.end[k]) ? 1 : 0;
    int base = (s == 0) ? 0 : segs.end[s - 1];
    int j = i - base;
    float4 v = segs.src[s][j];
    ushort4 o;
    o.x = f2bf(v.x); o.y = f2bf(v.y); o.z = f2bf(v.z); o.w = f2bf(v.w);
    segs.dst[s][j] = o;
}

// ---------------- generic C = A * B^T (bf16 in, fp32 out), 128x128 tile ----------------
// (kept only for the small router GEMM)
template<int ADD>
__global__ __launch_bounds__(256)
void gemm_bt(const unsigned short* __restrict__ A, const unsigned short* __restrict__ B,
             float* __restrict__ C, int M, int N, int K) {
    __shared__ unsigned short As[4096];  // [kc=4][m=128][8] bf16
    __shared__ unsigned short Bs[4096];  // [kc=4][n=128][8]
    const int tid  = threadIdx.x;
    const int lane = tid & 63;
    const int wave = tid >> 6;
    const int tm = blockIdx.x * 128;
    const int tn = blockIdx.y * 128;
    const int wm = (wave & 1) * 64;
    const int wn = (wave >> 1) * 64;
    const int quad = lane >> 4;
    const int tr   = lane & 15;

    f32x4 acc[4][4] = {};
    bf16x8 af[4], bfr[4];

    const int ua0 = tid,        am0 = ua0 & 127, ak0 = ua0 >> 7;
    const int ua1 = tid + 256,  am1 = ua1 & 127, ak1 = ua1 >> 7;

    auto issue = [&](int kt) {
        gld_lds16(A + (size_t)(tm + am0) * K + kt + ak0 * 8, &As[ua0 * 8]);
        gld_lds16(A + (size_t)(tm + am1) * K + kt + ak1 * 8, &As[ua1 * 8]);
        gld_lds16(B + (size_t)(tn + am0) * K + kt + ak0 * 8, &Bs[ua0 * 8]);
        gld_lds16(B + (size_t)(tn + am1) * K + kt + ak1 * 8, &Bs[ua1 * 8]);
    };
    auto rdfrags = [&]() {
        #pragma unroll
        for (int mi = 0; mi < 4; ++mi)
            af[mi] = *(const bf16x8*)&As[(quad * 128 + wm + mi * 16 + tr) * 8];
        #pragma unroll
        for (int ni = 0; ni < 4; ++ni)
            bfr[ni] = *(const bf16x8*)&Bs[(quad * 128 + wn + ni * 16 + tr) * 8];
    };
    auto mfmas = [&]() {
        #pragma unroll
        for (int mi = 0; mi < 4; ++mi)
            #pragma unroll
            for (int ni = 0; ni < 4; ++ni)
                acc[mi][ni] = __builtin_amdgcn_mfma_f32_16x16x32_bf16(af[mi], bfr[ni], acc[mi][ni], 0, 0, 0);
    };

    issue(0);
    asm volatile("s_waitcnt vmcnt(0)" ::: "memory");
    __syncthreads();
    rdfrags();
    for (int kt = 32; kt < K; kt += 32) {
        __syncthreads();
        issue(kt);
        mfmas();
        asm volatile("s_waitcnt vmcnt(0)" ::: "memory");
        __syncthreads();
        rdfrags();
    }
    mfmas();

    #pragma unroll
    for (int mi = 0; mi < 4; ++mi) {
        #pragma unroll
        for (int ni = 0; ni < 4; ++ni) {
            int col = tn + wn + ni * 16 + tr;
            #pragma unroll
            for (int r = 0; r < 4; ++r) {
                int row = tm + wm + mi * 16 + quad * 4 + r;
                size_t o = (size_t)row * N + col;
                float v = acc[mi][ni][r];
                if (ADD) v += C[o];
                C[o] = v;
            }
        }
    }
}

// common swizzle pieces for the ring kernels:
//   slotoff(row,cq) = (row>>1)*128 + ((((row&1)<<2)|cq) ^ ((row>>1)&7))*16
#define BARX() asm volatile("s_barrier" ::: "memory")
#define VMW(n) asm volatile("s_waitcnt vmcnt(" #n ")" ::: "memory")

// ---------------- fused GEMM1, 256x256 tile, BK=32 ring-4, 1.5-buffered frag pipeline -------
// h = silu(x @ Wg^T) * (x @ Wu^T), bf16 out. Virtual interleaved Wcat as before.
// Register-budget-aware software pipeline (round-7 spilled at 270 regs; this fits 248<=256):
//   - afLo (A m0-3) + bv (B n0-3): DOUBLE-buffered, prefetched for tile t+1 during tile t.
//   - afHi (A m4-7): 1.5-buffered — re-read for tile t+1 between the two 16-MFMA half-clusters
//     of tile t (after its last use at MMA-H), consumed at tile t+1's MMA-H.
// All 32 MFMAs of tile t consume only frags read during tile t-1 -> counted lgkm waits; the
// 12 ds_read_b128/wave retire under the MFMA burst (LDS pipe || matrix pipe).
// VMCNT LEDGER identical to round 7 (proven): 4 loads/stage, stage slot t+3 issued during t;
// end-of-tile VMW(4) leaves only that stage outstanding => at tile t start slots <= t+1
// complete, so prefetch-reads of slot (t+1)&3 are race-free. Overwrites barrier-separated.
// XCD map: each XCD owns 4 gm (2MB A, L2-resident) x all 32 gn (B streams).
#define RD_LO(AF, BV, r) { const char* _pa = lds + ((r) << 14); \
    const char* _pb = lds + 65536 + ((r) << 14); \
    AF[0] = *(const bf16x8*)(_pa + aoff[0]); \
    AF[1] = *(const bf16x8*)(_pa + aoff[1]); \
    AF[2] = *(const bf16x8*)(_pa + aoff[2]); \
    AF[3] = *(const bf16x8*)(_pa + aoff[3]); \
    BV[0] = *(const bf16x8*)(_pb + boff[0]); \
    BV[1] = *(const bf16x8*)(_pb + boff[1]); \
    BV[2] = *(const bf16x8*)(_pb + boff[2]); \
    BV[3] = *(const bf16x8*)(_pb + boff[3]); }

#define RD_HI(AF, r) { const char* _pa = lds + ((r) << 14); \
    AF[0] = *(const bf16x8*)(_pa + aoff[4]); \
    AF[1] = *(const bf16x8*)(_pa + aoff[5]); \
    AF[2] = *(const bf16x8*)(_pa + aoff[6]); \
    AF[3] = *(const bf16x8*)(_pa + aoff[7]); }

#define MMA16X(ACC, AF, BV) { __builtin_amdgcn_s_setprio(1); \
    _Pragma("unroll") \
    for (int _i = 0; _i < 4; ++_i) \
        _Pragma("unroll") \
        for (int _n = 0; _n < 4; ++_n) \
            ACC[_i][_n] = __builtin_amdgcn_mfma_f32_16x16x32_bf16(AF[_i], BV[_n], ACC[_i][_n], 0, 0, 0); \
    __builtin_amdgcn_s_setprio(0); }

__global__ __launch_bounds__(512, 2)
void gemm1_8ph(const unsigned short* __restrict__ Xb, const unsigned short* __restrict__ Wg,
               const unsigned short* __restrict__ Wu, unsigned short* __restrict__ Hb) {
    __shared__ __align__(16) char lds[131072];
    const int tid  = threadIdx.x;
    const int lane = tid & 63;
    const int wid  = tid >> 6;
    const int quad = lane >> 4;
    const int tr   = lane & 15;
    const int wm   = (wid >> 2) << 7;   // 0 / 128
    const int wn   = (wid & 3) << 6;    // 0 / 64 / 128 / 192

    // XCD map: xcd = bid&7 owns gm in {xcd*4 .. xcd*4+3} (A 2MB, L2-resident), gn sweeps 0..31.
    const int bid = blockIdx.x;
    const int u   = bid >> 3;
    const int gm  = (((bid & 7) << 2) | (u & 3)) << 8;
    const int gn  = (u >> 2) << 8;

    // staging thread map (inverse of the LDS swizzle, so gld_lds dest stays linear)
    const int vsw  = (tid & 7) ^ ((tid >> 3) & 7);
    const int rowb = ((tid >> 3) << 1) | (vsw >> 2);   // 0..127
    const int cq8  = (vsw & 3) << 3;

    const unsigned short* pA0 = Xb + (size_t)(gm + rowb) * HDIM + cq8;
    const unsigned short* pA1 = pA0 + (size_t)128 * HDIM;
    auto wsrc = [&](int R) -> const unsigned short* {
        const unsigned short* base = ((R >> 4) & 1) ? Wu : Wg;
        int sr = ((R >> 5) << 4) | (R & 15);
        return base + (size_t)sr * HDIM + cq8;
    };
    const unsigned short* pB0 = wsrc(gn + rowb);
    const unsigned short* pB1 = wsrc(gn + rowb + 128);

    int aoff[8], boff[4];
    #pragma unroll
    for (int i = 0; i < 8; ++i) {
        int row = wm + i * 16 + tr;
        aoff[i] = ((row >> 1) << 7) | (((((row & 1) << 2) | quad) ^ ((row >> 1) & 7)) << 4);
    }
    #pragma unroll
    for (int i = 0; i < 4; ++i) {
        int row = wn + i * 16 + tr;
        boff[i] = ((row >> 1) << 7) | (((((row & 1) << 2) | quad) ^ ((row >> 1) & 7)) << 4);
    }

    f32x4 accL[4][4] = {};
    f32x4 accH[4][4] = {};
    bf16x8 afLoA[4], bvA2[4], afLoB[4], bvB2[4], afHi[4];

    auto stageAB = [&](int slot, int kOff) {
        char* da = lds + (slot << 14) + (tid << 4);
        char* db = lds + 65536 + (slot << 14) + (tid << 4);
        gld_lds16(pA0 + kOff, da);
        gld_lds16(pA1 + kOff, da + 8192);
        gld_lds16(pB0 + kOff, db);
        gld_lds16(pB1 + kOff, db + 8192);
    };

    // prologue: stage tiles 0,1,2 (12 loads); vmcnt(4) -> slots 0 AND 1 complete
    stageAB(0, 0);
    stageAB(1, 32);
    stageAB(2, 64);
    VMW(4); BARX();
    RD_LO(afLoA, bvA2, 0);
    RD_HI(afHi, 0);

    for (int tt = 0; tt < 16; ++tt) {
        const int t0 = tt * 2, t1 = t0 + 1;
        // ---- tile t0 (cur = A-set): prefetch next lo/bv -> B-set, stage slot t0+3
        RD_LO(afLoB, bvB2, (t0 + 1) & 3);
        { int ts = t0 + 3; stageAB(ts & 3, (ts <= 31 ? ts : 31) << 5); }
        __builtin_amdgcn_sched_barrier(0);
        MMA16X(accH, afHi, bvA2);              // last use of cur afHi
        RD_HI(afHi, (t0 + 1) & 3);             // refill afHi for tile t1
        __builtin_amdgcn_sched_barrier(0);
        MMA16X(accL, afLoA, bvA2);
        VMW(4); BARX();
        // ---- tile t1 (cur = B-set)
        RD_LO(afLoA, bvA2, (t1 + 1) & 3);      // dummy in-bounds at tt=15 (unused)
        { int ts = t1 + 3; stageAB(ts & 3, (ts <= 31 ? ts : 31) << 5); }
        __builtin_amdgcn_sched_barrier(0);
        MMA16X(accH, afHi, bvB2);
        RD_HI(afHi, (t1 + 1) & 3);             // dummy in-bounds at tt=15 (unused)
        __builtin_amdgcn_sched_barrier(0);
        MMA16X(accL, afLoB, bvB2);
        VMW(4); BARX();
    }
    asm volatile("s_waitcnt vmcnt(0)" ::: "memory");  // drain DMA before block retires

    const size_t icb = (size_t)((gn + wn) >> 1) + tr;
    const int rbase = gm + wm + quad * 4;
    #pragma unroll
    for (int mi = 0; mi < 4; ++mi) {
        #pragma unroll
        for (int p = 0; p < 2; ++p) {
            #pragma unroll
            for (int r = 0; r < 4; ++r) {
                {
                    float g = accL[mi][2 * p][r], u2 = accL[mi][2 * p + 1][r];
                    float h = g / (1.0f + __expf(-g)) * u2;
                    Hb[(size_t)(rbase + mi * 16 + r) * IDIM + icb + 16 * p] = f2bf(h);
                }
                {
                    float g = accH[mi][2 * p][r], u2 = accH[mi][2 * p + 1][r];
                    float h = g / (1.0f + __expf(-g)) * u2;
                    Hb[(size_t)(rbase + 64 + mi * 16 + r) * IDIM + icb + 16 * p] = f2bf(h);
                }
            }
        }
    }
}

// ---------------- GEMM2 (down-proj): out += hbuf @ downb^T, 256x128 tile, BK=32 ring-4 ------
// Wave grid 4M x 2N (wave tile 64x64): 8 ds_read_b128/wave/tile. Reg-double-buffered frags
// (fits: acc 64 + frags 64 + addr < 256). VMW(3): 3 loads/stage, ledger as gemm1.
// XCD map: each XCD owns 4 gm x 8 gn (16MB working set).
#define RDT2(AF, BV, r) { const char* _pa = lds + ((r) << 14); \
    const char* _pb = lds + 65536 + ((r) << 13); \
    _Pragma("unroll") \
    for (int _i = 0; _i < 4; ++_i) AF[_i] = *(const bf16x8*)(_pa + aoff[_i]); \
    _Pragma("unroll") \
    for (int _n = 0; _n < 4; ++_n) BV[_n] = *(const bf16x8*)(_pb + boff[_n]); }

#define MMAT2(AF, BV) { __builtin_amdgcn_s_setprio(1); \
    _Pragma("unroll") \
    for (int _i = 0; _i < 4; ++_i) \
        _Pragma("unroll") \
        for (int _n = 0; _n < 4; ++_n) \
            acc[_i][_n] = __builtin_amdgcn_mfma_f32_16x16x32_bf16(AF[_i], BV[_n], acc[_i][_n], 0, 0, 0); \
    __builtin_amdgcn_s_setprio(0); }

__global__ __launch_bounds__(512, 2)
void gemm2_8ph(const unsigned short* __restrict__ A, const unsigned short* __restrict__ B,
               float* __restrict__ C) {
    __shared__ __align__(16) char lds[98304];
    const int K = IDIM, N = HDIM;
    const int tid  = threadIdx.x;
    const int lane = tid & 63;
    const int wid  = tid >> 6;
    const int quad = lane >> 4;
    const int tr   = lane & 15;
    const int wm   = (wid >> 1) << 6;   // 0 / 64 / 128 / 192
    const int wn   = (wid & 1) << 6;    // 0 / 64

    const int bid = blockIdx.x;
    const int u   = bid >> 3;
    const int gm  = (((bid & 7) << 2) | (u >> 3)) << 8;   // 0..7936
    const int gn  = (u & 7) << 7;                          // 0..896

    const int vsw  = (tid & 7) ^ ((tid >> 3) & 7);
    const int rowb = ((tid >> 3) << 1) | (vsw >> 2);   // 0..127
    const int cq8  = (vsw & 3) << 3;

    const unsigned short* pA0 = A + (size_t)(gm + rowb) * K + cq8;
    const unsigned short* pA1 = pA0 + (size_t)128 * K;
    const unsigned short* pB0 = B + (size_t)(gn + rowb) * K + cq8;

    int aoff[4], boff[4];
    #pragma unroll
    for (int i = 0; i < 4; ++i) {
        int row = wm + i * 16 + tr;
        aoff[i] = ((row >> 1) << 7) | (((((row & 1) << 2) | quad) ^ ((row >> 1) & 7)) << 4);
    }
    #pragma unroll
    for (int i = 0; i < 4; ++i) {
        int row = wn + i * 16 + tr;
        boff[i] = ((row >> 1) << 7) | (((((row & 1) << 2) | quad) ^ ((row >> 1) & 7)) << 4);
    }

    f32x4 acc[4][4] = {};
    bf16x8 afA[4], bvA[4], afB[4], bvB[4];

    auto stageAB = [&](int slot, int kOff) {
        char* da = lds + (slot << 14) + (tid << 4);
        char* db = lds + 65536 + (slot << 13) + (tid << 4);
        gld_lds16(pA0 + kOff, da);
        gld_lds16(pA1 + kOff, da + 8192);
        gld_lds16(pB0 + kOff, db);
    };

    // prologue: stage tiles 0,1,2 (9 loads); vmcnt(3) -> slots 0 AND 1 complete
    stageAB(0, 0);
    stageAB(1, 32);
    stageAB(2, 64);
    VMW(3); BARX();
    RDT2(afA, bvA, 0);

    for (int tt = 0; tt < 64; ++tt) {
        const int t0 = tt * 2, t1 = t0 + 1;
        // ---- tile t0
        RDT2(afB, bvB, t1 & 3);
        { int ts = t0 + 3; stageAB(ts & 3, (ts <= 127 ? ts : 127) << 5); }
        __builtin_amdgcn_sched_barrier(0);
        MMAT2(afA, bvA);
        VMW(3); BARX();
        // ---- tile t1
        RDT2(afA, bvA, (t1 + 1) & 3);   // dummy in-bounds at tt=63 (unused)
        { int ts = t1 + 3; stageAB(ts & 3, (ts <= 127 ? ts : 127) << 5); }
        __builtin_amdgcn_sched_barrier(0);
        MMAT2(afB, bvB);
        VMW(3); BARX();
    }
    asm volatile("s_waitcnt vmcnt(0)" ::: "memory");

    // epilogue: C += acc
    #pragma unroll
    for (int mi = 0; mi < 4; ++mi) {
        #pragma unroll
        for (int ni = 0; ni < 4; ++ni) {
            int col = gn + wn + ni * 16 + tr;
            #pragma unroll
            for (int r = 0; r < 4; ++r) {
                int row = gm + wm + mi * 16 + quad * 4 + r;
                size_t o = (size_t)row * N + col;
                C[o] += acc[mi][ni][r];
            }
        }
    }
}

// ---------------- batchnorm stats ----------------
__global__ void bn_stats(const float* __restrict__ gxy, float* __restrict__ sums, float* __restrict__ ssq) {
    const int j = threadIdx.x;
    const int b = blockIdx.x;
    float s = 0.f, q = 0.f;
    for (int r = 0; r < 32; ++r) {
        float v = gxy[(size_t)(b * 32 + r) * 256 + j];
        s += v; q += v * v;
    }
    atomicAdd(&sums[j], s);
    atomicAdd(&ssq[j], q);
}

// ---------------- routing: bn -> log_softmax -> top16 via candidate reduction ----------------
__global__ __launch_bounds__(256)
void routing_kernel(const float* __restrict__ gxy, const float* __restrict__ sums,
                    const float* __restrict__ ssq, int* __restrict__ oidx, float* __restrict__ owt) {
    const int lane = threadIdx.x & 63;
    const int t = blockIdx.x * 4 + (threadIdx.x >> 6);
    const float invT = 1.0f / (float)T_TOK;
    const float* g = gxy + (size_t)t * 256;

    float z[4];
    const int cols[4] = {lane, lane + 64, 128 + lane, 192 + lane};
    #pragma unroll
    for (int i = 0; i < 4; ++i) {
        int c = cols[i];
        float mu  = sums[c] * invT;
        float var = ssq[c] * invT - mu * mu;
        z[i] = (g[c] - mu) * rsqrtf(var + 1e-5f);
    }
    float mx = fmaxf(z[0], z[1]);
    float my = fmaxf(z[2], z[3]);
    #pragma unroll
    for (int m = 32; m >= 1; m >>= 1) {
        mx = fmaxf(mx, __shfl_xor(mx, m));
        my = fmaxf(my, __shfl_xor(my, m));
    }
    float sx = __expf(z[0] - mx) + __expf(z[1] - mx);
    float sy = __expf(z[2] - my) + __expf(z[3] - my);
    #pragma unroll
    for (int m = 32; m >= 1; m >>= 1) {
        sx += __shfl_xor(sx, m);
        sy += __shfl_xor(sy, m);
    }
    float lx0 = z[0] - (mx + __logf(sx)), lx1 = z[1] - (mx + __logf(sx));
    float ly0 = z[2] - (my + __logf(sy)), ly1 = z[3] - (my + __logf(sy));

    float aw = -INFINITY; int ai = 0;
    float bw = -INFINITY; int bi = 0;
    {
        float v0 = lx0, v1 = lx1;
        for (int i = 0; i < 16; ++i) {
            float v; int c;
            if (v0 >= v1) { v = v0; c = lane; } else { v = v1; c = lane + 64; }
            #pragma unroll
            for (int m = 32; m >= 1; m >>= 1) {
                float ov = __shfl_xor(v, m); int oc = __shfl_xor(c, m);
                if (ov > v || (ov == v && oc < c)) { v = ov; c = oc; }
            }
            if ((c & 63) == lane) { if (c < 64) v0 = -INFINITY; else v1 = -INFINITY; }
            if (lane == i) { aw = v; ai = c; }
        }
    }
    {
        float v0 = ly0, v1 = ly1;
        for (int i = 0; i < 16; ++i) {
            float v; int c;
            if (v0 >= v1) { v = v0; c = lane; } else { v = v1; c = lane + 64; }
            #pragma unroll
            for (int m = 32; m >= 1; m >>= 1) {
                float ov = __shfl_xor(v, m); int oc = __shfl_xor(c, m);
                if (ov > v || (ov == v && oc < c)) { v = ov; c = oc; }
            }
            if ((c & 63) == lane) { if (c < 64) v0 = -INFINITY; else v1 = -INFINITY; }
            if (lane == i) { bw = v; bi = c; }
        }
    }
    float cv[4];
    #pragma unroll
    for (int j = 0; j < 4; ++j) {
        int c = lane + 64 * j;
        cv[j] = __shfl(aw, c >> 4) + __shfl(bw, c & 15);
    }
    int myidx = 0; float myw = 0.f;
    for (int i = 0; i < 16; ++i) {
        float v = cv[0]; int c = lane;
        #pragma unroll
        for (int j = 1; j < 4; ++j) { int cc = lane + 64 * j; if (cv[j] > v) { v = cv[j]; c = cc; } }
        #pragma unroll
        for (int m = 32; m >= 1; m >>= 1) {
            float ov = __shfl_xor(v, m); int oc = __shfl_xor(c, m);
            if (ov > v || (ov == v && oc < c)) { v = ov; c = oc; }
        }
        #pragma unroll
        for (int j = 0; j < 4; ++j) if (c == lane + 64 * j) cv[j] = -INFINITY;
        int p = c >> 4, q = c & 15;
        int ex = __shfl(ai, p);
        int ey = __shfl(bi, q);
        if (lane == i) { myidx = ex * 128 + ey; myw = __expf(v); }
    }
    if (lane < 16) {
        oidx[t * TOPK + lane] = myidx;
        owt[t * TOPK + lane]  = myw;
    }
}

// ---------------- expert gather/combine (bf16 tables + bf16 x) ----------------
__global__ __launch_bounds__(256)
void expert_combine(const unsigned short* __restrict__ xb, const int* __restrict__ idx,
                    const float* __restrict__ wts, const unsigned short* __restrict__ ueb,
                    const unsigned short* __restrict__ deb, float* __restrict__ out) {
    const int t = blockIdx.x;
    const int tid = threadIdx.x;
    const int lane = tid & 63, wv = tid >> 6;
    __shared__ float part[TOPK * 4];
    __shared__ float sc[TOPK];
    ushort4 xv4 = ((const ushort4*)(xb + (size_t)t * HDIM))[tid];
    float x0 = bf2f(xv4.x), x1 = bf2f(xv4.y), x2 = bf2f(xv4.z), x3 = bf2f(xv4.w);
    int e[TOPK];
    #pragma unroll
    for (int k = 0; k < TOPK; ++k) e[k] = idx[t * TOPK + k];
    #pragma unroll
    for (int k = 0; k < TOPK; ++k) {
        ushort4 u4 = ((const ushort4*)(ueb + (size_t)e[k] * HDIM))[tid];
        float p = bf2f(u4.x) * x0 + bf2f(u4.y) * x1 + bf2f(u4.z) * x2 + bf2f(u4.w) * x3;
        #pragma unroll
        for (int m = 32; m >= 1; m >>= 1) p += __shfl_xor(p, m);
        if (lane == 0) part[k * 4 + wv] = p;
    }
    __syncthreads();
    if (tid < TOPK) {
        float s = part[tid * 4] + part[tid * 4 + 1] + part[tid * 4 + 2] + part[tid * 4 + 3];
        sc[tid] = s * wts[t * TOPK + tid];
    }
    __syncthreads();
    float4 acc = {0.f, 0.f, 0.f, 0.f};
    #pragma unroll
    for (int k = 0; k < TOPK; ++k) {
        float s = sc[k];
        ushort4 d4 = ((const ushort4*)(deb + (size_t)e[k] * HDIM))[tid];
        acc.x += s * bf2f(d4.x); acc.y += s * bf2f(d4.y);
        acc.z += s * bf2f(d4.z); acc.w += s * bf2f(d4.w);
    }
    ((float4*)(out + (size_t)t * HDIM))[tid] = acc;
}

extern "C" void kernel_launch(void* const* d_in, const int* in_sizes, int n_in,
                              void* d_out, int out_size, void* d_ws, size_t ws_size,
                              hipStream_t stream) {
    const float* x  = (const float*)d_in[0];
    const float* gw = (const float*)d_in[1];
    const float* uw = (const float*)d_in[2];
    const float* dw = (const float*)d_in[3];
    const float* wx = (const float*)d_in[4];
    const float* wy = (const float*)d_in[5];
    const float* ue = (const float*)d_in[6];
    const float* de = (const float*)d_in[7];
    float* out = (float*)d_out;

    char* ws = (char*)d_ws;
    size_t o = 0;
    auto alloc = [&](size_t bytes) { void* p = ws + o; o += (bytes + 255) & ~(size_t)255; return p; };
    unsigned short* xb    = (unsigned short*)alloc((size_t)T_TOK * HDIM * 2);
    unsigned short* gateb = (unsigned short*)alloc((size_t)IDIM * HDIM * 2);
    unsigned short* upb   = (unsigned short*)alloc((size_t)IDIM * HDIM * 2);
    unsigned short* downb = (unsigned short*)alloc((size_t)HDIM * IDIM * 2);
    unsigned short* wrb   = (unsigned short*)alloc((size_t)256 * HDIM * 2);
    unsigned short* ueb   = (unsigned short*)alloc((size_t)16384 * HDIM * 2);
    unsigned short* deb   = (unsigned short*)alloc((size_t)16384 * HDIM * 2);
    unsigned short* hbuf  = (unsigned short*)alloc((size_t)T_TOK * IDIM * 2);
    float* gxy  = (float*)alloc((size_t)T_TOK * 256 * 4);
    float* sums = (float*)alloc(256 * 4);
    float* ssq  = (float*)alloc(256 * 4);
    int*   idxs = (int*)alloc((size_t)T_TOK * TOPK * 4);
    float* wts  = (float*)alloc((size_t)T_TOK * TOPK * 4);

    // merged converts (8 segments)
    CvtSegs segs;
    const float* srcs[8] = {x, gw, uw, dw, wx, wy, ue, de};
    unsigned short* dsts[8] = {xb, gateb, upb, downb, wrb, wrb + SDIM * HDIM, ueb, deb};
    const int cnt4[8] = {T_TOK * HDIM / 4, IDIM * HDIM / 4, IDIM * HDIM / 4, IDIM * HDIM / 4,
                         SDIM * HDIM / 4, SDIM * HDIM / 4, 16384 * HDIM / 4, 16384 * HDIM / 4};
    int acc = 0;
    for (int i = 0; i < 8; ++i) {
        segs.src[i] = (const float4*)srcs[i];
        segs.dst[i] = (ushort4*)dsts[i];
        acc += cnt4[i];
        segs.end[i] = acc;
    }
    cvt_all_kernel<<<(acc + 255) / 256, 256, 0, stream>>>(segs);

    // router logits: gxy[T,256] = xb @ wrb^T
    hipMemsetAsync(sums, 0, 2 * 256 * 4, stream);  // sums+ssq contiguous
    gemm_bt<0><<<dim3(T_TOK / 128, 256 / 128), 256, 0, stream>>>(xb, wrb, gxy, T_TOK, 256, HDIM);
    bn_stats<<<256, 256, 0, stream>>>(gxy, sums, ssq);
    routing_kernel<<<T_TOK / 4, 256, 0, stream>>>(gxy, sums, ssq, idxs, wts);

    // expert branch writes out fully
    expert_combine<<<T_TOK, 256, 0, stream>>>(xb, idxs, wts, ueb, deb, out);

    // MLP branch: reg-pipelined ring-4 GEMMs
    gemm1_8ph<<<1024, 512, 0, stream>>>(xb, gateb, upb, hbuf);
    gemm2_8ph<<<256, 512, 0, stream>>>(hbuf, downb, out);
}